// Round 1
// baseline (1129.703 us; speedup 1.0000x reference)
//
#include <hip/hip_runtime.h>
#include <hip/hip_bf16.h>
#include <stdint.h>

using bf16 = __hip_bfloat16;
typedef __attribute__((ext_vector_type(4))) float f32x4;
typedef __attribute__((ext_vector_type(8))) short s16x8;
typedef __attribute__((ext_vector_type(4))) short s16x4;

// Problem constants
#define SEQN 2048
#define DIMD 1024   // DIMBED == DIMLAT == 1024
#define NB   16     // BATCH

// async global->LDS, 16B per lane, dest = wave-uniform base + lane*16
#define GLDS16(gp, lp)                                                      \
  __builtin_amdgcn_global_load_lds(                                         \
      (const __attribute__((address_space(1))) void*)(gp),                  \
      (__attribute__((address_space(3))) void*)(lp), 16, 0, 0)

// ---------------------------------------------------------------------------
// K0: convert fp32 weights to bf16. blockIdx.y selects Wq/Wk/Wv/Wg.
// Wqkv layout: rows 0..1023 = Wq, 1024..2047 = Wk, 2048..3071 = Wv (each [l][d])
// ---------------------------------------------------------------------------
__global__ void cvt_kernel(const float* __restrict__ Wq, const float* __restrict__ Wk,
                           const float* __restrict__ Wv, const float* __restrict__ Wg,
                           bf16* __restrict__ Wqkv, bf16* __restrict__ Wgb) {
  const int i = blockIdx.x * 256 + threadIdx.x;  // 0 .. 256K-1, 4 elems each
  const int which = blockIdx.y;
  const float* src = (which == 0) ? Wq : (which == 1) ? Wk : (which == 2) ? Wv : Wg;
  bf16* dst = (which < 3) ? (Wqkv + (size_t)which * DIMD * DIMD) : Wgb;
  f32x4 f = ((const f32x4*)src)[i];
  s16x4 pack;
#pragma unroll
  for (int j = 0; j < 4; ++j) {
    bf16 t = __float2bfloat16(f[j]);
    pack[j] = *reinterpret_cast<short*>(&t);
  }
  *reinterpret_cast<s16x4*>(dst + (size_t)i * 4) = pack;
}

// ---------------------------------------------------------------------------
// K1: LayerNorm over b (16 contiguous floats), eps = 1024 (faithful quirk).
// x[(s*1024+d)*16 + b]  ->  xt[(b*2048+s)*1024 + d]  (bf16)
// one thread per (s,d)
// ---------------------------------------------------------------------------
__global__ void ln_kernel(const float* __restrict__ x, const float* __restrict__ lnw,
                          const float* __restrict__ lnb, bf16* __restrict__ xt) {
  const int idx = blockIdx.x * 256 + threadIdx.x;  // s*1024 + d
  const int s = idx >> 10, d = idx & 1023;
  const float4* xp = reinterpret_cast<const float4*>(x + (size_t)idx * NB);
  float v[16];
#pragma unroll
  for (int j = 0; j < 4; ++j) reinterpret_cast<float4*>(v)[j] = xp[j];
  float mu = 0.f;
#pragma unroll
  for (int j = 0; j < 16; ++j) mu += v[j];
  mu *= (1.f / 16.f);
  float var = 0.f;
#pragma unroll
  for (int j = 0; j < 16; ++j) { float t = v[j] - mu; var += t * t; }
  var *= (1.f / 16.f);
  const float inv = rsqrtf(var + 1024.0f);  // LN_EPS = DIMBED
#pragma unroll
  for (int b = 0; b < 16; ++b) {
    float o = (v[b] - mu) * inv * lnw[b] + lnb[b];
    xt[((size_t)b * SEQN + s) * DIMD + d] = __float2bfloat16(o);
  }
}

// ---------------------------------------------------------------------------
// Generic 128x128 BK=32 bf16 MFMA GEMM, B^T layout (both A and B K-contiguous).
// C[m][n] = sum_k A[m][k] * B[n][k]
// MODE 0: store bf16 at C[coff + m*ldc + n]
// MODE 1: store bf16 exp(acc*escale) at C[coff + m*ldc + n]
// MODE 2: store fp32 acc + bias[n] at Cf[(m>>4)*16384 + n*16 + (m&15)]
// grid: (M/128, N/128, batches); batch strides sA/sB/sC in elements.
// ---------------------------------------------------------------------------
template <int MODE>
__global__ __launch_bounds__(256)
void gemm_bt(const bf16* __restrict__ Ag, const bf16* __restrict__ Bg,
             bf16* __restrict__ C, float* __restrict__ Cf,
             const float* __restrict__ bias,
             const int K, const int lda, const int ldb, const size_t ldc,
             const size_t sA, const size_t sB, const size_t sC,
             const float escale) {
  __shared__ bf16 As[128 * 32];  // 8 KiB
  __shared__ bf16 Bs[128 * 32];  // 8 KiB

  const int bz = blockIdx.z;
  const bf16* A = Ag + (size_t)bz * sA;
  const bf16* B = Bg + (size_t)bz * sB;
  const size_t coff = (size_t)bz * sC;

  const int t = threadIdx.x;
  const int w = t >> 6, lane = t & 63;
  const int m0 = blockIdx.x * 128, n0 = blockIdx.y * 128;

  // staging: thread t stages 8 bf16 (16B); rows sr and sr+64, k-cols sc..sc+7
  const int sr = t >> 2;
  const int sc = (t & 3) * 8;
  const bf16* gA0 = A + (size_t)(m0 + sr) * lda + sc;
  const bf16* gA1 = A + (size_t)(m0 + 64 + sr) * lda + sc;
  const bf16* gB0 = B + (size_t)(n0 + sr) * ldb + sc;
  const bf16* gB1 = B + (size_t)(n0 + 64 + sr) * ldb + sc;
  char* lA0 = (char*)As + w * 1024;
  char* lA1 = (char*)As + 4096 + w * 1024;
  char* lB0 = (char*)Bs + w * 1024;
  char* lB1 = (char*)Bs + 4096 + w * 1024;

  const int wr = w >> 1, wc = w & 1;  // wave -> 64x64 quadrant
  const int r16 = lane & 15, hi = lane >> 4;

  f32x4 acc[4][4] = {};

  for (int k0 = 0; k0 < K; k0 += 32) {
    __syncthreads();  // previous tile's ds_reads done before overwrite
    GLDS16(gA0 + k0, lA0);
    GLDS16(gA1 + k0, lA1);
    GLDS16(gB0 + k0, lB0);
    GLDS16(gB1 + k0, lB1);
    __syncthreads();  // vmcnt(0) drained by compiler before barrier

    s16x8 af[4], bfr[4];
#pragma unroll
    for (int mf = 0; mf < 4; ++mf)
      af[mf] = *(const s16x8*)&As[(wr * 64 + mf * 16 + r16) * 32 + hi * 8];
#pragma unroll
    for (int nf = 0; nf < 4; ++nf)
      bfr[nf] = *(const s16x8*)&Bs[(wc * 64 + nf * 16 + r16) * 32 + hi * 8];
#pragma unroll
    for (int mf = 0; mf < 4; ++mf)
#pragma unroll
      for (int nf = 0; nf < 4; ++nf)
        acc[mf][nf] = __builtin_amdgcn_mfma_f32_16x16x32_bf16(af[mf], bfr[nf], acc[mf][nf], 0, 0, 0);
  }

  // epilogue: C/D layout col = lane&15, row = (lane>>4)*4 + i   [m89/m91]
#pragma unroll
  for (int mf = 0; mf < 4; ++mf) {
#pragma unroll
    for (int nf = 0; nf < 4; ++nf) {
      f32x4 v = acc[mf][nf];
      const int gmb = m0 + wr * 64 + mf * 16 + hi * 4;
      const int gn = n0 + wc * 64 + nf * 16 + r16;
#pragma unroll
      for (int i = 0; i < 4; ++i) {
        const int gm = gmb + i;
        if (MODE == 0) {
          C[coff + (size_t)gm * ldc + gn] = __float2bfloat16(v[i]);
        } else if (MODE == 1) {
          C[coff + (size_t)gm * ldc + gn] = __float2bfloat16(__expf(v[i] * escale));
        } else {
          // gm = s*16 + b ; out[s*16384 + n*16 + b] = acc + bg[n]
          Cf[((size_t)(gm >> 4)) * (DIMD * NB) + (size_t)gn * NB + (gm & 15)] = v[i] + bias[gn];
        }
      }
    }
  }
}

// ---------------------------------------------------------------------------
// K4a: partial column sums of p over s-chunks. Z[b,t] = sum_s p[b,s,t].
// grid: (2048/256, 16, 8) ; Zp[(chunk*16 + b)*2048 + t]
// ---------------------------------------------------------------------------
__global__ void colsum_kernel(const bf16* __restrict__ p, float* __restrict__ Zp) {
  const int tcol = blockIdx.x * 256 + threadIdx.x;
  const int b = blockIdx.y;
  const int ch = blockIdx.z;
  const bf16* pp = p + ((size_t)b * SEQN + ch * 256) * SEQN + tcol;
  float s = 0.f;
#pragma unroll 8
  for (int i = 0; i < 256; ++i) s += __bfloat162float(pp[(size_t)i * SEQN]);
  Zp[((size_t)ch * NB + b) * SEQN + tcol] = s;
}

// K4b: Zinv[b*2048+t] = 1 / sum_chunks Zp
__global__ void zinv_kernel(const float* __restrict__ Zp, float* __restrict__ Zinv) {
  const int i = blockIdx.x * 256 + threadIdx.x;  // b*2048 + t
  float s = 0.f;
#pragma unroll
  for (int c = 0; c < 8; ++c) s += Zp[(size_t)c * (NB * SEQN) + i];
  Zinv[i] = 1.0f / s;
}

// ---------------------------------------------------------------------------
// K5: v''[b][l][t] = v[b][t][l] * Zinv[b,t]   (v = QKV cols 2048..3071)
// LDS 64x64 tile transpose, pitch 66 (2 lanes/bank on transposed read)
// grid: (32 tblk, 16 lblk, 16 b)
// ---------------------------------------------------------------------------
__global__ void vtrans_kernel(const bf16* __restrict__ QKV, const float* __restrict__ Zinv,
                              bf16* __restrict__ vpp) {
  __shared__ bf16 tile[64][66];
  const int b = blockIdx.z;
  const int t0 = blockIdx.x * 64;
  const int l0 = blockIdx.y * 64;
  const int tid = threadIdx.x;
  const int col = tid & 63, rw = tid >> 6;
#pragma unroll
  for (int i = 0; i < 16; ++i) {
    const int r = i * 4 + rw;  // t-row
    tile[r][col] = QKV[((size_t)b * SEQN + t0 + r) * 3072 + 2048 + l0 + col];
  }
  __syncthreads();
  const float z = Zinv[b * SEQN + t0 + col];
#pragma unroll
  for (int i = 0; i < 16; ++i) {
    const int lr = i * 4 + rw;  // l-row
    vpp[((size_t)b * DIMD + l0 + lr) * SEQN + t0 + col] =
        __float2bfloat16(__bfloat162float(tile[col][lr]) * z);
  }
}

// ---------------------------------------------------------------------------
extern "C" void kernel_launch(void* const* d_in, const int* in_sizes, int n_in,
                              void* d_out, int out_size, void* d_ws, size_t ws_size,
                              hipStream_t stream) {
  const float* x   = (const float*)d_in[0];
  const float* Wq  = (const float*)d_in[1];
  const float* Wk  = (const float*)d_in[2];
  const float* Wv  = (const float*)d_in[3];
  const float* Wg  = (const float*)d_in[4];
  const float* bg  = (const float*)d_in[5];
  const float* lnw = (const float*)d_in[6];
  const float* lnb = (const float*)d_in[7];
  float* out = (float*)d_out;

  // workspace layout (≈393 MiB)
  char* ws = (char*)d_ws;
  size_t off = 0;
  auto alloc = [&](size_t bytes) {
    char* p = ws + off;
    off += (bytes + 255) & ~(size_t)255;
    return p;
  };
  bf16* Wqkv = (bf16*)alloc((size_t)3072 * DIMD * 2);        // 6 MiB
  bf16* Wgb  = (bf16*)alloc((size_t)DIMD * DIMD * 2);        // 2 MiB
  bf16* xt   = (bf16*)alloc((size_t)NB * SEQN * DIMD * 2);   // 64 MiB
  bf16* QKV  = (bf16*)alloc((size_t)NB * SEQN * 3072 * 2);   // 192 MiB
  bf16* p    = (bf16*)alloc((size_t)NB * SEQN * SEQN * 2);   // 128 MiB
  float* Zp  = (float*)alloc((size_t)8 * NB * SEQN * 4);     // 1 MiB
  float* Zinv = (float*)alloc((size_t)NB * SEQN * 4);        // 128 KiB
  bf16* vpp = xt;   // alias: xt dead after GEMM1
  bf16* fth = QKV;  // alias: QKV dead after vtrans

  const dim3 blk(256);

  // K0: weight conversion
  cvt_kernel<<<dim3(1024, 4), blk, 0, stream>>>(Wq, Wk, Wv, Wg, Wqkv, Wgb);
  // K1: LayerNorm + transpose to (b,s,d) bf16
  ln_kernel<<<dim3(SEQN * DIMD / 256), blk, 0, stream>>>(x, lnw, lnb, xt);
  // K2 GEMM1: QKV[m=b*2048+s][3072] = xt @ [Wq;Wk;Wv]^T
  gemm_bt<0><<<dim3(256, 24, 1), blk, 0, stream>>>(
      xt, Wqkv, QKV, nullptr, nullptr,
      /*K*/ DIMD, /*lda*/ DIMD, /*ldb*/ DIMD, /*ldc*/ 3072,
      0, 0, 0, 0.f);
  // K3 GEMM2 (batched over b): p[b,s,t] = exp((q_b @ k_b^T)/32)  bf16
  gemm_bt<1><<<dim3(16, 16, 16), blk, 0, stream>>>(
      QKV, QKV + 1024, p, nullptr, nullptr,
      /*K*/ DIMD, /*lda*/ 3072, /*ldb*/ 3072, /*ldc*/ SEQN,
      (size_t)SEQN * 3072, (size_t)SEQN * 3072, (size_t)SEQN * SEQN, 0.03125f);
  // K4: column sums over s  ->  Zinv[b,t]
  colsum_kernel<<<dim3(8, 16, 8), blk, 0, stream>>>(p, Zp);
  zinv_kernel<<<dim3(NB * SEQN / 256), blk, 0, stream>>>(Zp, Zinv);
  // K5: v''[b,l,t] = v[b,t,l] * Zinv[b,t]
  vtrans_kernel<<<dim3(32, 16, 16), blk, 0, stream>>>(QKV, Zinv, vpp);
  // K6 GEMM3 (batched): ftheta[(s*16+b)*1024+l] = p_b @ v''_b^T
  gemm_bt<0><<<dim3(16, 8, 16), blk, 0, stream>>>(
      p, vpp, fth, nullptr, nullptr,
      /*K*/ SEQN, /*lda*/ SEQN, /*ldb*/ SEQN, /*ldc*/ (size_t)NB * DIMD,
      (size_t)SEQN * SEQN, (size_t)DIMD * SEQN, DIMD, 0.f);
  // K7 GEMM4: out[s,d,b] = ftheta @ Wg^T + bg
  gemm_bt<2><<<dim3(256, 8, 1), blk, 0, stream>>>(
      fth, Wgb, nullptr, out, bg,
      /*K*/ DIMD, /*lda*/ DIMD, /*ldb*/ DIMD, /*ldc*/ 0,
      0, 0, 0, 0.f);
}

// Round 2
// 885.267 us; speedup vs baseline: 1.2761x; 1.2761x over previous
//
#include <hip/hip_runtime.h>
#include <hip/hip_bf16.h>
#include <stdint.h>

using bf16 = __hip_bfloat16;
typedef __attribute__((ext_vector_type(4))) float f32x4;
typedef __attribute__((ext_vector_type(8))) short s16x8;
typedef __attribute__((ext_vector_type(4))) short s16x4;

// Problem constants
#define SEQN 2048
#define DIMD 1024   // DIMBED == DIMLAT == 1024
#define NB   16     // BATCH

// async global->LDS, 16B per lane, dest = wave-uniform base + lane*16
#define GLDS16(gp, lp)                                                      \
  __builtin_amdgcn_global_load_lds(                                         \
      (const __attribute__((address_space(1))) void*)(gp),                  \
      (__attribute__((address_space(3))) void*)(lp), 16, 0, 0)

// ---------------------------------------------------------------------------
// K0: convert fp32 weights to bf16.
// ---------------------------------------------------------------------------
__global__ void cvt_kernel(const float* __restrict__ Wq, const float* __restrict__ Wk,
                           const float* __restrict__ Wv, const float* __restrict__ Wg,
                           bf16* __restrict__ Wqkv, bf16* __restrict__ Wgb) {
  const int i = blockIdx.x * 256 + threadIdx.x;
  const int which = blockIdx.y;
  const float* src = (which == 0) ? Wq : (which == 1) ? Wk : (which == 2) ? Wv : Wg;
  bf16* dst = (which < 3) ? (Wqkv + (size_t)which * DIMD * DIMD) : Wgb;
  f32x4 f = ((const f32x4*)src)[i];
  s16x4 pack;
#pragma unroll
  for (int j = 0; j < 4; ++j) {
    bf16 t = __float2bfloat16(f[j]);
    pack[j] = *reinterpret_cast<short*>(&t);
  }
  *reinterpret_cast<s16x4*>(dst + (size_t)i * 4) = pack;
}

// ---------------------------------------------------------------------------
// K1: LayerNorm over b (16 contiguous floats), eps = 1024 (faithful quirk).
// x[(s*1024+d)*16 + b]  ->  xt[(b*2048+s)*1024 + d]  (bf16)
// ---------------------------------------------------------------------------
__global__ void ln_kernel(const float* __restrict__ x, const float* __restrict__ lnw,
                          const float* __restrict__ lnb, bf16* __restrict__ xt) {
  const int idx = blockIdx.x * 256 + threadIdx.x;  // s*1024 + d
  const int s = idx >> 10, d = idx & 1023;
  const float4* xp = reinterpret_cast<const float4*>(x + (size_t)idx * NB);
  float v[16];
#pragma unroll
  for (int j = 0; j < 4; ++j) reinterpret_cast<float4*>(v)[j] = xp[j];
  float mu = 0.f;
#pragma unroll
  for (int j = 0; j < 16; ++j) mu += v[j];
  mu *= (1.f / 16.f);
  float var = 0.f;
#pragma unroll
  for (int j = 0; j < 16; ++j) { float t = v[j] - mu; var += t * t; }
  var *= (1.f / 16.f);
  const float inv = rsqrtf(var + 1024.0f);  // LN_EPS = DIMBED
#pragma unroll
  for (int b = 0; b < 16; ++b) {
    float o = (v[b] - mu) * inv * lnw[b] + lnb[b];
    xt[((size_t)b * SEQN + s) * DIMD + d] = __float2bfloat16(o);
  }
}

// ---------------------------------------------------------------------------
// 256x256-tile bf16 MFMA GEMM, BK=32, 8 waves (2M x 4N), 4-deep LDS ring,
// counted vmcnt (12/8/4/0), st_16x32 XOR swizzle, setprio around MFMA,
// XCD-chunked tile swizzle. B^T layout: C[m][n] = sum_k A[m][k]*B[n][k].
// MODE 0: C[coff+m*ldc+n] = bf16(acc)
// MODE 1: C[coff+m*ldc+n] = bf16(exp(acc*escale))
// MODE 2: Cf[(m>>4)*16384 + n*16 + (m&15)] = acc + bias[n]
// Requires: M%256==0, N%256==0, K%32==0, K/32>=4, gridDim.x%8==0.
// ---------------------------------------------------------------------------
template <int MODE>
__global__ __launch_bounds__(512, 2)
void gemm256(const bf16* __restrict__ Ag, const bf16* __restrict__ Bg,
             bf16* __restrict__ C, float* __restrict__ Cf,
             const float* __restrict__ bias,
             const int K, const int lda, const int ldb, const size_t ldc,
             const size_t sA, const size_t sB, const size_t sC,
             const int tn, const float escale) {
  __shared__ bf16 sm[4][2][256 * 32];  // 4 ring bufs x (A,B) x 16KB = 128 KiB

  // XCD-chunked bijective swizzle: XCD j owns a contiguous tile range.
  const int nwg = gridDim.x;
  const int flat = blockIdx.x;
  const int tile = (flat & 7) * (nwg >> 3) + (flat >> 3);
  const int m0 = (tile / tn) * 256;
  const int n0 = (tile % tn) * 256;

  const int bz = blockIdx.z;
  const bf16* A = Ag + (size_t)bz * sA;
  const bf16* B = Bg + (size_t)bz * sB;
  const size_t coff = (size_t)bz * sC;

  const int tid = threadIdx.x;
  const int w = tid >> 6;
  const int lane = tid & 63;
  const int wr = w >> 2, wc = w & 3;      // wave -> (2M x 4N) of 128x64 outputs
  const int r16 = lane & 15, hi = lane >> 4;

  // --- staging coords: thread stages 8 bf16 (16B); LDS linear, source
  // pre-swizzled so that LDS[row][c] = G[row][c ^ s(row)], s(row)=((row>>3)&1)<<4
  const int srow = tid >> 2;                                   // 0..127
  const int scol = ((tid & 3) * 8) ^ (((srow >> 3) & 1) << 4); // pre-swizzled k-col
  const bf16* gA0 = A + (size_t)(m0 + srow) * lda + scol;
  const bf16* gA1 = A + (size_t)(m0 + 128 + srow) * lda + scol;
  const bf16* gB0 = B + (size_t)(n0 + srow) * ldb + scol;
  const bf16* gB1 = B + (size_t)(n0 + 128 + srow) * ldb + scol;
  const int wbase = w * 512;  // wave-uniform element offset into 8K-elem region

  // --- fragment read coords (same XOR on the read side)
  const int fcol = (hi * 8) ^ (((r16 >> 3) & 1) << 4);
  const int aoff = (wr * 128 + r16) * 32 + fcol;  // + mf*512
  const int boff = (wc * 64 + r16) * 32 + fcol;   // + nf*512

  f32x4 acc[8][4] = {};
  const int NT = K >> 5;

#define STAGE(tt, bb) do {                                                  \
    const int k0_ = (tt) << 5;                                              \
    bf16* sA_ = &sm[bb][0][0];                                              \
    bf16* sB_ = &sm[bb][1][0];                                              \
    GLDS16(gA0 + k0_, sA_ + wbase);                                         \
    GLDS16(gA1 + k0_, sA_ + 4096 + wbase);                                  \
    GLDS16(gB0 + k0_, sB_ + wbase);                                         \
    GLDS16(gB1 + k0_, sB_ + 4096 + wbase);                                  \
  } while (0)

#define COMPUTE(bb) do {                                                    \
    const bf16* pA_ = &sm[bb][0][aoff];                                     \
    const bf16* pB_ = &sm[bb][1][boff];                                     \
    s16x8 af[8], bfr[4];                                                    \
    _Pragma("unroll")                                                       \
    for (int mf = 0; mf < 8; ++mf) af[mf] = *(const s16x8*)(pA_ + mf * 512);\
    _Pragma("unroll")                                                       \
    for (int nf = 0; nf < 4; ++nf) bfr[nf] = *(const s16x8*)(pB_ + nf * 512);\
    __builtin_amdgcn_s_setprio(1);                                          \
    _Pragma("unroll")                                                       \
    for (int mf = 0; mf < 8; ++mf)                                          \
      _Pragma("unroll")                                                     \
      for (int nf = 0; nf < 4; ++nf)                                        \
        acc[mf][nf] = __builtin_amdgcn_mfma_f32_16x16x32_bf16(af[mf], bfr[nf], acc[mf][nf], 0, 0, 0); \
    __builtin_amdgcn_s_setprio(0);                                          \
  } while (0)

#define BAR() asm volatile("s_barrier" ::: "memory")
#define VMW(n) asm volatile("s_waitcnt vmcnt(" #n ")" ::: "memory")

  // prologue: fill 3 ring slots
  STAGE(0, 0);
  STAGE(1, 1);
  STAGE(2, 2);

  int t = 0;
  for (; t < NT - 3; ++t) {
    STAGE(t + 3, (t + 3) & 3);  // into buf freed at end of iter t-1
    VMW(12);                    // own tile-t loads done (12 newer in flight)
    BAR();                      // everyone's tile-t loads landed
    COMPUTE(t & 3);
    BAR();                      // all reads of buf[t&3] done before next STAGE
  }
  // tail: 3 peeled iterations, counted drain 8 -> 4 -> 0
  VMW(8);  BAR(); COMPUTE(t & 3); ++t;
  VMW(4);  BAR(); COMPUTE(t & 3); ++t;
  VMW(0);  BAR(); COMPUTE(t & 3);

#undef STAGE
#undef COMPUTE
#undef BAR
#undef VMW

  // epilogue: C/D layout col = lane&15, row = (lane>>4)*4 + i
#pragma unroll
  for (int mf = 0; mf < 8; ++mf) {
#pragma unroll
    for (int nf = 0; nf < 4; ++nf) {
      f32x4 v = acc[mf][nf];
      const int gm0 = m0 + wr * 128 + mf * 16 + hi * 4;
      const int gn = n0 + wc * 64 + nf * 16 + r16;
#pragma unroll
      for (int i = 0; i < 4; ++i) {
        const int gm = gm0 + i;
        if (MODE == 0) {
          C[coff + (size_t)gm * ldc + gn] = __float2bfloat16(v[i]);
        } else if (MODE == 1) {
          C[coff + (size_t)gm * ldc + gn] = __float2bfloat16(__expf(v[i] * escale));
        } else {
          // gm = s*16 + b ; out[s*16384 + n*16 + b] = acc + bg[n]
          Cf[((size_t)(gm >> 4)) * (DIMD * NB) + (size_t)gn * NB + (gm & 15)] = v[i] + bias[gn];
        }
      }
    }
  }
}

// ---------------------------------------------------------------------------
// K4a: partial column sums of p over s-chunks. Z[b,t] = sum_s p[b,s,t].
// ---------------------------------------------------------------------------
__global__ void colsum_kernel(const bf16* __restrict__ p, float* __restrict__ Zp) {
  const int tcol = blockIdx.x * 256 + threadIdx.x;
  const int b = blockIdx.y;
  const int ch = blockIdx.z;
  const bf16* pp = p + ((size_t)b * SEQN + ch * 256) * SEQN + tcol;
  float s = 0.f;
#pragma unroll 8
  for (int i = 0; i < 256; ++i) s += __bfloat162float(pp[(size_t)i * SEQN]);
  Zp[((size_t)ch * NB + b) * SEQN + tcol] = s;
}

// K4b: Zinv[b*2048+t] = 1 / sum_chunks Zp
__global__ void zinv_kernel(const float* __restrict__ Zp, float* __restrict__ Zinv) {
  const int i = blockIdx.x * 256 + threadIdx.x;
  float s = 0.f;
#pragma unroll
  for (int c = 0; c < 8; ++c) s += Zp[(size_t)c * (NB * SEQN) + i];
  Zinv[i] = 1.0f / s;
}

// ---------------------------------------------------------------------------
// K5: v''[b][l][t] = v[b][t][l] * Zinv[b,t]   (v = QKV cols 2048..3071)
// ---------------------------------------------------------------------------
__global__ void vtrans_kernel(const bf16* __restrict__ QKV, const float* __restrict__ Zinv,
                              bf16* __restrict__ vpp) {
  __shared__ bf16 tile[64][66];
  const int b = blockIdx.z;
  const int t0 = blockIdx.x * 64;
  const int l0 = blockIdx.y * 64;
  const int tid = threadIdx.x;
  const int col = tid & 63, rw = tid >> 6;
#pragma unroll
  for (int i = 0; i < 16; ++i) {
    const int r = i * 4 + rw;
    tile[r][col] = QKV[((size_t)b * SEQN + t0 + r) * 3072 + 2048 + l0 + col];
  }
  __syncthreads();
  const float z = Zinv[b * SEQN + t0 + col];
#pragma unroll
  for (int i = 0; i < 16; ++i) {
    const int lr = i * 4 + rw;
    vpp[((size_t)b * DIMD + l0 + lr) * SEQN + t0 + col] =
        __float2bfloat16(__bfloat162float(tile[col][lr]) * z);
  }
}

// ---------------------------------------------------------------------------
extern "C" void kernel_launch(void* const* d_in, const int* in_sizes, int n_in,
                              void* d_out, int out_size, void* d_ws, size_t ws_size,
                              hipStream_t stream) {
  const float* x   = (const float*)d_in[0];
  const float* Wq  = (const float*)d_in[1];
  const float* Wk  = (const float*)d_in[2];
  const float* Wv  = (const float*)d_in[3];
  const float* Wg  = (const float*)d_in[4];
  const float* bg  = (const float*)d_in[5];
  const float* lnw = (const float*)d_in[6];
  const float* lnb = (const float*)d_in[7];
  float* out = (float*)d_out;

  char* ws = (char*)d_ws;
  size_t off = 0;
  auto alloc = [&](size_t bytes) {
    char* p = ws + off;
    off += (bytes + 255) & ~(size_t)255;
    return p;
  };
  bf16* Wqkv = (bf16*)alloc((size_t)3072 * DIMD * 2);        // 6 MiB
  bf16* Wgb  = (bf16*)alloc((size_t)DIMD * DIMD * 2);        // 2 MiB
  bf16* xt   = (bf16*)alloc((size_t)NB * SEQN * DIMD * 2);   // 64 MiB
  bf16* QKV  = (bf16*)alloc((size_t)NB * SEQN * 3072 * 2);   // 192 MiB
  bf16* p    = (bf16*)alloc((size_t)NB * SEQN * SEQN * 2);   // 128 MiB
  float* Zp  = (float*)alloc((size_t)8 * NB * SEQN * 4);     // 1 MiB
  float* Zinv = (float*)alloc((size_t)NB * SEQN * 4);        // 128 KiB
  bf16* vpp = xt;   // alias: xt dead after GEMM1
  bf16* fth = QKV;  // alias: QKV dead after vtrans

  const dim3 blk(256);
  const dim3 blk512(512);

  // K0: weight conversion
  cvt_kernel<<<dim3(1024, 4), blk, 0, stream>>>(Wq, Wk, Wv, Wg, Wqkv, Wgb);
  // K1: LayerNorm + transpose to (b,s,d) bf16
  ln_kernel<<<dim3(SEQN * DIMD / 256), blk, 0, stream>>>(x, lnw, lnb, xt);
  // K2 GEMM1: QKV[m=b*2048+s][3072] = xt @ [Wq;Wk;Wv]^T   (128x12 tiles)
  gemm256<0><<<dim3(128 * 12, 1, 1), blk512, 0, stream>>>(
      xt, Wqkv, QKV, nullptr, nullptr,
      /*K*/ DIMD, /*lda*/ DIMD, /*ldb*/ DIMD, /*ldc*/ 3072,
      0, 0, 0, /*tn*/ 12, 0.f);
  // K3 GEMM2 (batched over b): p[b,s,t] = exp((q_b @ k_b^T)/32)   (8x8 tiles)
  gemm256<1><<<dim3(8 * 8, 1, 16), blk512, 0, stream>>>(
      QKV, QKV + 1024, p, nullptr, nullptr,
      /*K*/ DIMD, /*lda*/ 3072, /*ldb*/ 3072, /*ldc*/ SEQN,
      (size_t)SEQN * 3072, (size_t)SEQN * 3072, (size_t)SEQN * SEQN, /*tn*/ 8, 0.03125f);
  // K4: column sums over s  ->  Zinv[b,t]
  colsum_kernel<<<dim3(8, 16, 8), blk, 0, stream>>>(p, Zp);
  zinv_kernel<<<dim3(NB * SEQN / 256), blk, 0, stream>>>(Zp, Zinv);
  // K5: v''[b,l,t] = v[b,t,l] * Zinv[b,t]
  vtrans_kernel<<<dim3(32, 16, 16), blk, 0, stream>>>(QKV, Zinv, vpp);
  // K6 GEMM3 (batched): ftheta[(s*16+b)*1024+l] = p_b @ v''_b^T   (8x4 tiles)
  gemm256<0><<<dim3(8 * 4, 1, 16), blk512, 0, stream>>>(
      p, vpp, fth, nullptr, nullptr,
      /*K*/ SEQN, /*lda*/ SEQN, /*ldb*/ SEQN, /*ldc*/ (size_t)NB * DIMD,
      (size_t)SEQN * SEQN, (size_t)DIMD * SEQN, DIMD, /*tn*/ 4, 0.f);
  // K7 GEMM4: out[s,d,b] = ftheta @ Wg^T + bg   (128x4 tiles)
  gemm256<2><<<dim3(128 * 4, 1, 1), blk512, 0, stream>>>(
      fth, Wgb, nullptr, out, bg,
      /*K*/ DIMD, /*lda*/ DIMD, /*ldb*/ DIMD, /*ldc*/ 0,
      0, 0, 0, /*tn*/ 4, 0.f);
}

// Round 3
// 860.331 us; speedup vs baseline: 1.3131x; 1.0290x over previous
//
#include <hip/hip_runtime.h>
#include <hip/hip_bf16.h>
#include <stdint.h>

using bf16 = __hip_bfloat16;
typedef __attribute__((ext_vector_type(4))) float f32x4;
typedef __attribute__((ext_vector_type(8))) short s16x8;
typedef __attribute__((ext_vector_type(4))) short s16x4;

// Problem constants
#define SEQN 2048
#define DIMD 1024   // DIMBED == DIMLAT == 1024
#define NB   16     // BATCH

// async global->LDS, 16B per lane: dest = wave-uniform base + lane*16 (implicit)
#define GLDS16(gp, lp)                                                      \
  __builtin_amdgcn_global_load_lds(                                         \
      (const __attribute__((address_space(1))) void*)(gp),                  \
      (__attribute__((address_space(3))) void*)(lp), 16, 0, 0)

// ---------------------------------------------------------------------------
// K0: convert fp32 weights to bf16.
// ---------------------------------------------------------------------------
__global__ void cvt_kernel(const float* __restrict__ Wq, const float* __restrict__ Wk,
                           const float* __restrict__ Wv, const float* __restrict__ Wg,
                           bf16* __restrict__ Wqkv, bf16* __restrict__ Wgb) {
  const int i = blockIdx.x * 256 + threadIdx.x;
  const int which = blockIdx.y;
  const float* src = (which == 0) ? Wq : (which == 1) ? Wk : (which == 2) ? Wv : Wg;
  bf16* dst = (which < 3) ? (Wqkv + (size_t)which * DIMD * DIMD) : Wgb;
  f32x4 f = ((const f32x4*)src)[i];
  s16x4 pack;
#pragma unroll
  for (int j = 0; j < 4; ++j) {
    bf16 t = __float2bfloat16(f[j]);
    pack[j] = *reinterpret_cast<short*>(&t);
  }
  *reinterpret_cast<s16x4*>(dst + (size_t)i * 4) = pack;
}

// ---------------------------------------------------------------------------
// K1: LayerNorm over b (16 contiguous floats), eps = 1024 (faithful quirk).
// x[(s*1024+d)*16 + b]  ->  xt[(b*2048+s)*1024 + d]  (bf16)
// ---------------------------------------------------------------------------
__global__ void ln_kernel(const float* __restrict__ x, const float* __restrict__ lnw,
                          const float* __restrict__ lnb, bf16* __restrict__ xt) {
  const int idx = blockIdx.x * 256 + threadIdx.x;  // s*1024 + d
  const int s = idx >> 10, d = idx & 1023;
  const float4* xp = reinterpret_cast<const float4*>(x + (size_t)idx * NB);
  float v[16];
#pragma unroll
  for (int j = 0; j < 4; ++j) reinterpret_cast<float4*>(v)[j] = xp[j];
  float mu = 0.f;
#pragma unroll
  for (int j = 0; j < 16; ++j) mu += v[j];
  mu *= (1.f / 16.f);
  float var = 0.f;
#pragma unroll
  for (int j = 0; j < 16; ++j) { float t = v[j] - mu; var += t * t; }
  var *= (1.f / 16.f);
  const float inv = rsqrtf(var + 1024.0f);  // LN_EPS = DIMBED
#pragma unroll
  for (int b = 0; b < 16; ++b) {
    float o = (v[b] - mu) * inv * lnw[b] + lnb[b];
    xt[((size_t)b * SEQN + s) * DIMD + d] = __float2bfloat16(o);
  }
}

// ---------------------------------------------------------------------------
// 256x256-tile bf16 MFMA GEMM, BK=64, 8 waves (2M x 4N), 8-phase schedule:
// per K-tile 4 phases of {ds_read subtile || 2 quarter-stages -> s_barrier ->
// 16 MFMA (setprio) -> s_barrier}, double-buffered LDS, counted vmcnt(4/2),
// 3-bit XOR LDS swizzle (both sides), XCD-chunked tile swizzle.
// B^T layout: C[m][n] = sum_k A[m][k]*B[n][k]
// MODE 0: C[coff+m*ldc+n] = bf16(acc)
// MODE 1: C[coff+m*ldc+n] = bf16(exp(acc*escale))
// MODE 2: Cf[(m>>4)*16384 + n*16 + (m&15)] = acc + bias[n]
// Requires: M%256==0, N%256==0, K%64==0, gridDim.x%8==0.
// ---------------------------------------------------------------------------
template <int MODE>
__global__ __launch_bounds__(512, 2)
void gemm256(const bf16* __restrict__ Ag, const bf16* __restrict__ Bg,
             bf16* __restrict__ C, float* __restrict__ Cf,
             const float* __restrict__ bias,
             const int K, const int lda, const int ldb, const size_t ldc,
             const size_t sA, const size_t sB, const size_t sC,
             const int tn, const float escale) {
  // [buf][A=0/B=1][4 quarters x 4096 elems]; quarter = 64 rows x 64 k, row-major
  __shared__ bf16 sm[2][2][16384];  // 128 KiB

  // XCD-chunked bijective swizzle (gridDim.x % 8 == 0)
  const int nwg = gridDim.x;
  const int flat = blockIdx.x;
  const int tile = (flat & 7) * (nwg >> 3) + (flat >> 3);
  const int m0 = (tile / tn) * 256;
  const int n0 = (tile % tn) * 256;

  const int bz = blockIdx.z;
  const bf16* A = Ag + (size_t)bz * sA;
  const bf16* B = Bg + (size_t)bz * sB;
  const size_t coff = (size_t)bz * sC;

  const int tid = threadIdx.x;
  const int w = tid >> 6;
  const int lane = tid & 63;
  const int wr = w >> 2, wc = w & 3;      // wave -> 128x64 output block
  const int r16 = lane & 15, hi = lane >> 4;
  const int xorb = r16 & 7;               // row&7 (frag-row bases are x16)

  // --- staging coords: thread stages one row-slice of a 64x64 quarter (16B)
  const int slrow = tid >> 3;                       // 0..63
  const int sgrp = (tid & 7) ^ (slrow & 7);         // pre-swizzled col group
  const bf16* gSA = A + (size_t)(m0 + slrow) * lda + sgrp * 8;
  const bf16* gSB = B + (size_t)(n0 + slrow) * ldb + sgrp * 8;
  const int w512 = w * 512;  // wave-uniform LDS elem offset (lane*8 implicit)

  // --- fragment read offsets within a quarter (elems), per k-half
  const int off0 = r16 * 64 + ((0 + hi) ^ xorb) * 8;   // k-half 0
  const int off1 = r16 * 64 + ((4 + hi) ^ xorb) * 8;   // k-half 1

  f32x4 acc[8][4] = {};
  s16x8 aF[4][2], bF[2][2];
  const int NT = K >> 6;

#define SQ_A(q, kt, bb)                                                      \
  GLDS16(gSA + (size_t)((q) * 64) * lda + (size_t)(kt) * 64,                 \
         &sm[bb][0][(q) * 4096 + w512])
#define SQ_B(q, kt, bb)                                                      \
  GLDS16(gSB + (size_t)((q) * 64) * ldb + (size_t)(kt) * 64,                 \
         &sm[bb][1][(q) * 4096 + w512])

#define READ_A(mh, bb) do {                                                  \
    const bf16* pa_ = &sm[bb][0][(2 * wr + (mh)) * 4096];                    \
    _Pragma("unroll")                                                        \
    for (int sub = 0; sub < 4; ++sub) {                                      \
      aF[sub][0] = *(const s16x8*)(pa_ + sub * 1024 + off0);                 \
      aF[sub][1] = *(const s16x8*)(pa_ + sub * 1024 + off1);                 \
    }                                                                        \
  } while (0)

#define READ_B(nh, bb) do {                                                  \
    const bf16* pb_ = &sm[bb][1][wc * 4096 + (nh) * 2048];                   \
    _Pragma("unroll")                                                        \
    for (int j = 0; j < 2; ++j) {                                            \
      bF[j][0] = *(const s16x8*)(pb_ + j * 1024 + off0);                     \
      bF[j][1] = *(const s16x8*)(pb_ + j * 1024 + off1);                     \
    }                                                                        \
  } while (0)

#define MFMA_Q(mh, nh) do {                                                  \
    __builtin_amdgcn_s_setprio(1);                                           \
    _Pragma("unroll")                                                        \
    for (int k = 0; k < 2; ++k)                                              \
      _Pragma("unroll")                                                      \
      for (int j = 0; j < 2; ++j)                                            \
        _Pragma("unroll")                                                    \
        for (int sub = 0; sub < 4; ++sub)                                    \
          acc[(mh) * 4 + sub][(nh) * 2 + j] = __builtin_amdgcn_mfma_f32_16x16x32_bf16( \
              aF[sub][k], bF[j][k], acc[(mh) * 4 + sub][(nh) * 2 + j], 0, 0, 0); \
    __builtin_amdgcn_s_setprio(0);                                           \
  } while (0)

#define BAR() asm volatile("s_barrier" ::: "memory")
#define VMW(n) asm volatile("s_waitcnt vmcnt(" #n ")" ::: "memory")

  // prologue: stage tile 0 into buf 0 (same issue order as steady state)
  SQ_B(0, 0, 0); SQ_B(1, 0, 0); SQ_B(2, 0, 0); SQ_B(3, 0, 0);
  SQ_A(0, 0, 0); SQ_A(2, 0, 0); SQ_A(1, 0, 0); SQ_A(3, 0, 0);
  VMW(2);  // all but Aq1,Aq3 landed (those gate at phase-1 end)
  BAR();

  int t = 0;
  for (; t < NT - 1; ++t) {
    const int cb = t & 1, nb = cb ^ 1, nk = t + 1;
    // phase 0 (mh=0, nh=0)
    READ_A(0, cb); READ_B(0, cb);
    SQ_B(0, nk, nb); SQ_B(1, nk, nb);
    BAR(); MFMA_Q(0, 0); BAR();
    // phase 1 (mh=0, nh=1)
    READ_B(1, cb);
    SQ_B(2, nk, nb); SQ_B(3, nk, nb);
    VMW(4);  // Aq1,Aq3 of tile t landed (4 newer B-stages may fly)
    BAR(); MFMA_Q(0, 1); BAR();
    // phase 2 (mh=1, nh=0)
    READ_A(1, cb); READ_B(0, cb);
    SQ_A(0, nk, nb); SQ_A(2, nk, nb);
    BAR(); MFMA_Q(1, 0); BAR();
    // phase 3 (mh=1, nh=1)
    READ_B(1, cb);
    SQ_A(1, nk, nb); SQ_A(3, nk, nb);
    VMW(2);  // tile t+1 B*,Aq0,Aq2 landed (Aq1,Aq3 may fly)
    BAR(); MFMA_Q(1, 1); BAR();
  }
  // last tile: no staging; drain Aq1,Aq3 before the A-half swap
  {
    const int cb = t & 1;
    READ_A(0, cb); READ_B(0, cb); BAR(); MFMA_Q(0, 0); BAR();
    READ_B(1, cb); VMW(0); BAR(); MFMA_Q(0, 1); BAR();
    READ_A(1, cb); READ_B(0, cb); BAR(); MFMA_Q(1, 0); BAR();
    READ_B(1, cb); BAR(); MFMA_Q(1, 1); BAR();
  }

#undef SQ_A
#undef SQ_B
#undef READ_A
#undef READ_B
#undef MFMA_Q
#undef BAR
#undef VMW

  // epilogue: C/D layout col = lane&15, row = (lane>>4)*4 + i
#pragma unroll
  for (int mf = 0; mf < 8; ++mf) {
#pragma unroll
    for (int nf = 0; nf < 4; ++nf) {
      f32x4 v = acc[mf][nf];
      const int gm0 = m0 + wr * 128 + mf * 16 + hi * 4;
      const int gn = n0 + wc * 64 + nf * 16 + r16;
#pragma unroll
      for (int i = 0; i < 4; ++i) {
        const int gm = gm0 + i;
        if (MODE == 0) {
          C[coff + (size_t)gm * ldc + gn] = __float2bfloat16(v[i]);
        } else if (MODE == 1) {
          C[coff + (size_t)gm * ldc + gn] = __float2bfloat16(__expf(v[i] * escale));
        } else {
          // gm = s*16 + b ; out[s*16384 + n*16 + b] = acc + bg[n]
          Cf[((size_t)(gm >> 4)) * (DIMD * NB) + (size_t)gn * NB + (gm & 15)] = v[i] + bias[gn];
        }
      }
    }
  }
}

// ---------------------------------------------------------------------------
// K4a: partial column sums of p over s-chunks. Z[b,t] = sum_s p[b,s,t].
// ---------------------------------------------------------------------------
__global__ void colsum_kernel(const bf16* __restrict__ p, float* __restrict__ Zp) {
  const int tcol = blockIdx.x * 256 + threadIdx.x;
  const int b = blockIdx.y;
  const int ch = blockIdx.z;
  const bf16* pp = p + ((size_t)b * SEQN + ch * 256) * SEQN + tcol;
  float s = 0.f;
#pragma unroll 8
  for (int i = 0; i < 256; ++i) s += __bfloat162float(pp[(size_t)i * SEQN]);
  Zp[((size_t)ch * NB + b) * SEQN + tcol] = s;
}

// K4b: Zinv[b*2048+t] = 1 / sum_chunks Zp
__global__ void zinv_kernel(const float* __restrict__ Zp, float* __restrict__ Zinv) {
  const int i = blockIdx.x * 256 + threadIdx.x;
  float s = 0.f;
#pragma unroll
  for (int c = 0; c < 8; ++c) s += Zp[(size_t)c * (NB * SEQN) + i];
  Zinv[i] = 1.0f / s;
}

// ---------------------------------------------------------------------------
// K5: v''[b][l][t] = v[b][t][l] * Zinv[b,t]   (v = QKV cols 2048..3071)
// ---------------------------------------------------------------------------
__global__ void vtrans_kernel(const bf16* __restrict__ QKV, const float* __restrict__ Zinv,
                              bf16* __restrict__ vpp) {
  __shared__ bf16 tile[64][66];
  const int b = blockIdx.z;
  const int t0 = blockIdx.x * 64;
  const int l0 = blockIdx.y * 64;
  const int tid = threadIdx.x;
  const int col = tid & 63, rw = tid >> 6;
#pragma unroll
  for (int i = 0; i < 16; ++i) {
    const int r = i * 4 + rw;
    tile[r][col] = QKV[((size_t)b * SEQN + t0 + r) * 3072 + 2048 + l0 + col];
  }
  __syncthreads();
  const float z = Zinv[b * SEQN + t0 + col];
#pragma unroll
  for (int i = 0; i < 16; ++i) {
    const int lr = i * 4 + rw;
    vpp[((size_t)b * DIMD + l0 + lr) * SEQN + t0 + col] =
        __float2bfloat16(__bfloat162float(tile[col][lr]) * z);
  }
}

// ---------------------------------------------------------------------------
extern "C" void kernel_launch(void* const* d_in, const int* in_sizes, int n_in,
                              void* d_out, int out_size, void* d_ws, size_t ws_size,
                              hipStream_t stream) {
  const float* x   = (const float*)d_in[0];
  const float* Wq  = (const float*)d_in[1];
  const float* Wk  = (const float*)d_in[2];
  const float* Wv  = (const float*)d_in[3];
  const float* Wg  = (const float*)d_in[4];
  const float* bg  = (const float*)d_in[5];
  const float* lnw = (const float*)d_in[6];
  const float* lnb = (const float*)d_in[7];
  float* out = (float*)d_out;

  char* ws = (char*)d_ws;
  size_t off = 0;
  auto alloc = [&](size_t bytes) {
    char* p = ws + off;
    off += (bytes + 255) & ~(size_t)255;
    return p;
  };
  bf16* Wqkv = (bf16*)alloc((size_t)3072 * DIMD * 2);        // 6 MiB
  bf16* Wgb  = (bf16*)alloc((size_t)DIMD * DIMD * 2);        // 2 MiB
  bf16* xt   = (bf16*)alloc((size_t)NB * SEQN * DIMD * 2);   // 64 MiB
  bf16* QKV  = (bf16*)alloc((size_t)NB * SEQN * 3072 * 2);   // 192 MiB
  bf16* p    = (bf16*)alloc((size_t)NB * SEQN * SEQN * 2);   // 128 MiB
  float* Zp  = (float*)alloc((size_t)8 * NB * SEQN * 4);     // 1 MiB
  float* Zinv = (float*)alloc((size_t)NB * SEQN * 4);        // 128 KiB
  bf16* vpp = xt;   // alias: xt dead after GEMM1
  bf16* fth = QKV;  // alias: QKV dead after vtrans

  const dim3 blk(256);
  const dim3 blk512(512);

  // K0: weight conversion
  cvt_kernel<<<dim3(1024, 4), blk, 0, stream>>>(Wq, Wk, Wv, Wg, Wqkv, Wgb);
  // K1: LayerNorm + transpose to (b,s,d) bf16
  ln_kernel<<<dim3(SEQN * DIMD / 256), blk, 0, stream>>>(x, lnw, lnb, xt);
  // K2 GEMM1: QKV[m=b*2048+s][3072] = xt @ [Wq;Wk;Wv]^T   (128x12 tiles)
  gemm256<0><<<dim3(128 * 12, 1, 1), blk512, 0, stream>>>(
      xt, Wqkv, QKV, nullptr, nullptr,
      /*K*/ DIMD, /*lda*/ DIMD, /*ldb*/ DIMD, /*ldc*/ 3072,
      0, 0, 0, /*tn*/ 12, 0.f);
  // K3 GEMM2 (batched over b): p[b,s,t] = exp((q_b @ k_b^T)/32)   (8x8 tiles)
  gemm256<1><<<dim3(8 * 8, 1, 16), blk512, 0, stream>>>(
      QKV, QKV + 1024, p, nullptr, nullptr,
      /*K*/ DIMD, /*lda*/ 3072, /*ldb*/ 3072, /*ldc*/ SEQN,
      (size_t)SEQN * 3072, (size_t)SEQN * 3072, (size_t)SEQN * SEQN, /*tn*/ 8, 0.03125f);
  // K4: column sums over s  ->  Zinv[b,t]
  colsum_kernel<<<dim3(8, 16, 8), blk, 0, stream>>>(p, Zp);
  zinv_kernel<<<dim3(NB * SEQN / 256), blk, 0, stream>>>(Zp, Zinv);
  // K5: v''[b,l,t] = v[b,t,l] * Zinv[b,t]
  vtrans_kernel<<<dim3(32, 16, 16), blk, 0, stream>>>(QKV, Zinv, vpp);
  // K6 GEMM3 (batched): ftheta[(s*16+b)*1024+l] = p_b @ v''_b^T   (8x4 tiles)
  gemm256<0><<<dim3(8 * 4, 1, 16), blk512, 0, stream>>>(
      p, vpp, fth, nullptr, nullptr,
      /*K*/ SEQN, /*lda*/ SEQN, /*ldb*/ SEQN, /*ldc*/ (size_t)NB * DIMD,
      (size_t)SEQN * SEQN, (size_t)DIMD * SEQN, DIMD, /*tn*/ 4, 0.f);
  // K7 GEMM4: out[s,d,b] = ftheta @ Wg^T + bg   (128x4 tiles)
  gemm256<2><<<dim3(128 * 4, 1, 1), blk512, 0, stream>>>(
      fth, Wgb, nullptr, out, bg,
      /*K*/ DIMD, /*lda*/ DIMD, /*ldb*/ DIMD, /*ldc*/ 0,
      0, 0, 0, /*tn*/ 4, 0.f);
}

// Round 4
// 847.118 us; speedup vs baseline: 1.3336x; 1.0156x over previous
//
#include <hip/hip_runtime.h>
#include <hip/hip_bf16.h>
#include <stdint.h>

using bf16 = __hip_bfloat16;
typedef __attribute__((ext_vector_type(4))) float f32x4;
typedef __attribute__((ext_vector_type(8))) short s16x8;
typedef __attribute__((ext_vector_type(4))) short s16x4;

// Problem constants
#define SEQN 2048
#define DIMD 1024   // DIMBED == DIMLAT == 1024
#define NB   16     // BATCH

// async global->LDS, 16B per lane: dest = wave-uniform base + lane*16 (implicit)
#define GLDS16(gp, lp)                                                      \
  __builtin_amdgcn_global_load_lds(                                         \
      (const __attribute__((address_space(1))) void*)(gp),                  \
      (__attribute__((address_space(3))) void*)(lp), 16, 0, 0)

// ---------------------------------------------------------------------------
// K0: convert fp32 weights to bf16.
// ---------------------------------------------------------------------------
__global__ void cvt_kernel(const float* __restrict__ Wq, const float* __restrict__ Wk,
                           const float* __restrict__ Wv, const float* __restrict__ Wg,
                           bf16* __restrict__ Wqkv, bf16* __restrict__ Wgb) {
  const int i = blockIdx.x * 256 + threadIdx.x;
  const int which = blockIdx.y;
  const float* src = (which == 0) ? Wq : (which == 1) ? Wk : (which == 2) ? Wv : Wg;
  bf16* dst = (which < 3) ? (Wqkv + (size_t)which * DIMD * DIMD) : Wgb;
  f32x4 f = ((const f32x4*)src)[i];
  s16x4 pack;
#pragma unroll
  for (int j = 0; j < 4; ++j) {
    bf16 t = __float2bfloat16(f[j]);
    pack[j] = *reinterpret_cast<short*>(&t);
  }
  *reinterpret_cast<s16x4*>(dst + (size_t)i * 4) = pack;
}

// ---------------------------------------------------------------------------
// K1: LayerNorm over b (16 contiguous floats), eps = 1024 (faithful quirk).
// x[(s*1024+d)*16 + b]  ->  xt[(b*2048+s)*1024 + d]  (bf16)
// ---------------------------------------------------------------------------
__global__ void ln_kernel(const float* __restrict__ x, const float* __restrict__ lnw,
                          const float* __restrict__ lnb, bf16* __restrict__ xt) {
  const int idx = blockIdx.x * 256 + threadIdx.x;  // s*1024 + d
  const int s = idx >> 10, d = idx & 1023;
  const float4* xp = reinterpret_cast<const float4*>(x + (size_t)idx * NB);
  float v[16];
#pragma unroll
  for (int j = 0; j < 4; ++j) reinterpret_cast<float4*>(v)[j] = xp[j];
  float mu = 0.f;
#pragma unroll
  for (int j = 0; j < 16; ++j) mu += v[j];
  mu *= (1.f / 16.f);
  float var = 0.f;
#pragma unroll
  for (int j = 0; j < 16; ++j) { float t = v[j] - mu; var += t * t; }
  var *= (1.f / 16.f);
  const float inv = rsqrtf(var + 1024.0f);  // LN_EPS = DIMBED
#pragma unroll
  for (int b = 0; b < 16; ++b) {
    float o = (v[b] - mu) * inv * lnw[b] + lnb[b];
    xt[((size_t)b * SEQN + s) * DIMD + d] = __float2bfloat16(o);
  }
}

// ---------------------------------------------------------------------------
// 256x256-tile bf16 MFMA GEMM, BK=64, 8 waves (2M x 4N), 4 phases/K-tile:
// B-quarter held fully in regs (read once/tile), all 8 next-tile stages
// issued in P0/P1, counted vmcnt(8)@P1 / vmcnt(2)@P3 with >=2-phase slack,
// double-buffered LDS, 3-bit XOR swizzle (both sides), XCD-chunked tiles.
// B^T layout: C[m][n] = sum_k A[m][k]*B[n][k]
// MODE 0: C[coff+m*ldc+n] = bf16(acc)
// MODE 1: C[coff+m*ldc+n] = bf16(exp(acc*escale)); atomicAdd col-sums to Cf[bz*SEQN+n]
// MODE 2: Cf[(m>>4)*16384 + n*16 + (m&15)] = acc + bias[n]
// Requires: M%256==0, N%256==0, K%64==0, K/64>=2, gridDim.x%8==0.
// ---------------------------------------------------------------------------
template <int MODE>
__global__ __launch_bounds__(512, 2)
void gemm256(const bf16* __restrict__ Ag, const bf16* __restrict__ Bg,
             bf16* __restrict__ C, float* __restrict__ Cf,
             const float* __restrict__ bias,
             const int K, const int lda, const int ldb, const size_t ldc,
             const size_t sA, const size_t sB, const size_t sC,
             const int tn, const float escale) {
  // [buf][A=0/B=1][4 quarters x 4096 elems]; quarter = 64 rows x 64 k, row-major
  __shared__ bf16 sm[2][2][16384];  // 128 KiB

  // XCD-chunked bijective swizzle (gridDim.x % 8 == 0)
  const int nwg = gridDim.x;
  const int flat = blockIdx.x;
  const int tile = (flat & 7) * (nwg >> 3) + (flat >> 3);
  const int m0 = (tile / tn) * 256;
  const int n0 = (tile % tn) * 256;

  const int bz = blockIdx.z;
  const bf16* A = Ag + (size_t)bz * sA;
  const bf16* B = Bg + (size_t)bz * sB;
  const size_t coff = (size_t)bz * sC;

  const int tid = threadIdx.x;
  const int w = tid >> 6;
  const int lane = tid & 63;
  const int wr = w >> 2, wc = w & 3;      // wave -> 128x64 output block
  const int r16 = lane & 15, hi = lane >> 4;
  const int xorb = r16 & 7;               // row&7 (frag-row bases are x16)

  // --- staging coords: thread stages one row-slice of a 64x64 quarter (16B)
  const int slrow = tid >> 3;                       // 0..63
  const int sgrp = (tid & 7) ^ (slrow & 7);         // pre-swizzled col group
  const bf16* gSA = A + (size_t)(m0 + slrow) * lda + sgrp * 8;
  const bf16* gSB = B + (size_t)(n0 + slrow) * ldb + sgrp * 8;
  const int w512 = w * 512;  // wave-uniform LDS elem offset (lane*8 implicit)

  // --- fragment read offsets within a quarter (elems), per k-half
  const int off0 = r16 * 64 + ((0 + hi) ^ xorb) * 8;   // k-half 0
  const int off1 = r16 * 64 + ((4 + hi) ^ xorb) * 8;   // k-half 1

  f32x4 acc[8][4] = {};
  s16x8 aF[4][2], bF[4][2];
  const int NT = K >> 6;

#define SQ_A(q, kt, bb)                                                      \
  GLDS16(gSA + (size_t)((q) * 64) * lda + (size_t)(kt) * 64,                 \
         &sm[bb][0][(q) * 4096 + w512])
#define SQ_B(q, kt, bb)                                                      \
  GLDS16(gSB + (size_t)((q) * 64) * ldb + (size_t)(kt) * 64,                 \
         &sm[bb][1][(q) * 4096 + w512])

#define READ_A(mh, bb) do {                                                  \
    const bf16* pa_ = &sm[bb][0][(2 * wr + (mh)) * 4096];                    \
    _Pragma("unroll")                                                        \
    for (int sub = 0; sub < 4; ++sub) {                                      \
      aF[sub][0] = *(const s16x8*)(pa_ + sub * 1024 + off0);                 \
      aF[sub][1] = *(const s16x8*)(pa_ + sub * 1024 + off1);                 \
    }                                                                        \
  } while (0)

#define READ_B_ALL(bb) do {                                                  \
    const bf16* pb_ = &sm[bb][1][wc * 4096];                                 \
    _Pragma("unroll")                                                        \
    for (int j = 0; j < 4; ++j) {                                            \
      bF[j][0] = *(const s16x8*)(pb_ + j * 1024 + off0);                     \
      bF[j][1] = *(const s16x8*)(pb_ + j * 1024 + off1);                     \
    }                                                                        \
  } while (0)

#define MFMA_Q(mh, nh) do {                                                  \
    __builtin_amdgcn_s_setprio(1);                                           \
    _Pragma("unroll")                                                        \
    for (int k = 0; k < 2; ++k)                                              \
      _Pragma("unroll")                                                      \
      for (int j = 0; j < 2; ++j)                                            \
        _Pragma("unroll")                                                    \
        for (int sub = 0; sub < 4; ++sub)                                    \
          acc[(mh) * 4 + sub][(nh) * 2 + j] = __builtin_amdgcn_mfma_f32_16x16x32_bf16( \
              aF[sub][k], bF[(nh) * 2 + j][k], acc[(mh) * 4 + sub][(nh) * 2 + j], 0, 0, 0); \
    __builtin_amdgcn_s_setprio(0);                                           \
  } while (0)

#define BAR() asm volatile("s_barrier" ::: "memory")
#define VMW(n) asm volatile("s_waitcnt vmcnt(" #n ")" ::: "memory")

  // prologue: stage tile 0 into buf 0 (steady-state issue order)
  SQ_B(0, 0, 0); SQ_B(1, 0, 0); SQ_B(2, 0, 0); SQ_B(3, 0, 0);
  SQ_A(0, 0, 0); SQ_A(2, 0, 0); SQ_A(1, 0, 0); SQ_A(3, 0, 0);
  VMW(2);  // B0-3,A0,A2 landed; A1,A3 in flight (loop invariant)
  BAR();

  int t = 0;
  for (; t < NT - 1; ++t) {
    const int cb = t & 1, nb = cb ^ 1, nk = t + 1;
    // P0 (mh=0, nh=0): all B + A-half-0 reads; stage next-tile B quarters
    READ_B_ALL(cb); READ_A(0, cb);
    SQ_B(0, nk, nb); SQ_B(1, nk, nb); SQ_B(2, nk, nb); SQ_B(3, nk, nb);
    BAR(); MFMA_Q(0, 0); BAR();
    // P1 (mh=0, nh=1): stage next-tile A quarters; gate A1,A3 of tile t
    SQ_A(0, nk, nb); SQ_A(2, nk, nb); SQ_A(1, nk, nb); SQ_A(3, nk, nb);
    VMW(8);  // drains A1(cb),A3(cb) issued 4 phases ago
    BAR(); MFMA_Q(0, 1); BAR();
    // P2 (mh=1, nh=0)
    READ_A(1, cb);
    BAR(); MFMA_Q(1, 0); BAR();
    // P3 (mh=1, nh=1): gate next tile's B0-3,A0,A2 (issued 2-3 phases ago)
    VMW(2);
    BAR(); MFMA_Q(1, 1); BAR();
  }
  // tail tile: no staging; drain remaining A1,A3 before A-half swap
  {
    const int cb = t & 1;
    READ_B_ALL(cb); READ_A(0, cb); BAR(); MFMA_Q(0, 0); BAR();
    VMW(0); BAR(); MFMA_Q(0, 1); BAR();
    READ_A(1, cb); BAR(); MFMA_Q(1, 0);
    MFMA_Q(1, 1);
  }

#undef SQ_A
#undef SQ_B
#undef READ_A
#undef READ_B_ALL
#undef MFMA_Q
#undef BAR
#undef VMW

  // epilogue: C/D layout col = lane&15, row = (lane>>4)*4 + i
  float cs[4] = {0.f, 0.f, 0.f, 0.f};  // MODE1 per-thread column partials
#pragma unroll
  for (int mf = 0; mf < 8; ++mf) {
#pragma unroll
    for (int nf = 0; nf < 4; ++nf) {
      f32x4 v = acc[mf][nf];
      const int gm0 = m0 + wr * 128 + mf * 16 + hi * 4;
      const int gn = n0 + wc * 64 + nf * 16 + r16;
#pragma unroll
      for (int i = 0; i < 4; ++i) {
        const int gm = gm0 + i;
        if (MODE == 0) {
          C[coff + (size_t)gm * ldc + gn] = __float2bfloat16(v[i]);
        } else if (MODE == 1) {
          const float e = __expf(v[i] * escale);
          C[coff + (size_t)gm * ldc + gn] = __float2bfloat16(e);
          cs[nf] += e;
        } else {
          // gm = s*16 + b ; out[s*16384 + n*16 + b] = acc + bg[n]
          Cf[((size_t)(gm >> 4)) * (DIMD * NB) + (size_t)gn * NB + (gm & 15)] = v[i] + bias[gn];
        }
      }
    }
  }
  if (MODE == 1) {
    // reduce the 4 row-owning lanes of each column (lanes differing in bits 4,5)
#pragma unroll
    for (int nf = 0; nf < 4; ++nf) {
      cs[nf] += __shfl_xor(cs[nf], 16);
      cs[nf] += __shfl_xor(cs[nf], 32);
    }
    if (hi == 0) {
#pragma unroll
      for (int nf = 0; nf < 4; ++nf) {
        const int gn = n0 + wc * 64 + nf * 16 + r16;
        atomicAdd(&Cf[(size_t)bz * SEQN + gn], cs[nf]);
      }
    }
  }
}

// ---------------------------------------------------------------------------
// K5: v''[b][l][t] = v[b][t][l] / Zsum[b,t]   (v = QKV cols 2048..3071)
// ---------------------------------------------------------------------------
__global__ void vtrans_kernel(const bf16* __restrict__ QKV, const float* __restrict__ Zsum,
                              bf16* __restrict__ vpp) {
  __shared__ bf16 tile[64][66];
  const int b = blockIdx.z;
  const int t0 = blockIdx.x * 64;
  const int l0 = blockIdx.y * 64;
  const int tid = threadIdx.x;
  const int col = tid & 63, rw = tid >> 6;
#pragma unroll
  for (int i = 0; i < 16; ++i) {
    const int r = i * 4 + rw;
    tile[r][col] = QKV[((size_t)b * SEQN + t0 + r) * 3072 + 2048 + l0 + col];
  }
  __syncthreads();
  const float z = 1.0f / Zsum[b * SEQN + t0 + col];
#pragma unroll
  for (int i = 0; i < 16; ++i) {
    const int lr = i * 4 + rw;
    vpp[((size_t)b * DIMD + l0 + lr) * SEQN + t0 + col] =
        __float2bfloat16(__bfloat162float(tile[col][lr]) * z);
  }
}

// ---------------------------------------------------------------------------
extern "C" void kernel_launch(void* const* d_in, const int* in_sizes, int n_in,
                              void* d_out, int out_size, void* d_ws, size_t ws_size,
                              hipStream_t stream) {
  const float* x   = (const float*)d_in[0];
  const float* Wq  = (const float*)d_in[1];
  const float* Wk  = (const float*)d_in[2];
  const float* Wv  = (const float*)d_in[3];
  const float* Wg  = (const float*)d_in[4];
  const float* bg  = (const float*)d_in[5];
  const float* lnw = (const float*)d_in[6];
  const float* lnb = (const float*)d_in[7];
  float* out = (float*)d_out;

  char* ws = (char*)d_ws;
  size_t off = 0;
  auto alloc = [&](size_t bytes) {
    char* p = ws + off;
    off += (bytes + 255) & ~(size_t)255;
    return p;
  };
  bf16* Wqkv = (bf16*)alloc((size_t)3072 * DIMD * 2);        // 6 MiB
  bf16* Wgb  = (bf16*)alloc((size_t)DIMD * DIMD * 2);        // 2 MiB
  bf16* xt   = (bf16*)alloc((size_t)NB * SEQN * DIMD * 2);   // 64 MiB
  bf16* QKV  = (bf16*)alloc((size_t)NB * SEQN * 3072 * 2);   // 192 MiB
  bf16* p    = (bf16*)alloc((size_t)NB * SEQN * SEQN * 2);   // 128 MiB
  float* Zsum = (float*)alloc((size_t)NB * SEQN * 4);        // 128 KiB
  bf16* vpp = xt;   // alias: xt dead after GEMM1
  bf16* fth = QKV;  // alias: QKV dead after vtrans

  const dim3 blk(256);
  const dim3 blk512(512);

  // K0: weight conversion
  cvt_kernel<<<dim3(1024, 4), blk, 0, stream>>>(Wq, Wk, Wv, Wg, Wqkv, Wgb);
  // K1: LayerNorm + transpose to (b,s,d) bf16
  ln_kernel<<<dim3(SEQN * DIMD / 256), blk, 0, stream>>>(x, lnw, lnb, xt);
  // zero the softmax-denominator accumulator (GEMM2 epilogue atomicAdds into it)
  hipMemsetAsync(Zsum, 0, (size_t)NB * SEQN * 4, stream);
  // K2 GEMM1: QKV[m=b*2048+s][3072] = xt @ [Wq;Wk;Wv]^T   (128x12 tiles)
  gemm256<0><<<dim3(128 * 12, 1, 1), blk512, 0, stream>>>(
      xt, Wqkv, QKV, nullptr, nullptr,
      /*K*/ DIMD, /*lda*/ DIMD, /*ldb*/ DIMD, /*ldc*/ 3072,
      0, 0, 0, /*tn*/ 12, 0.f);
  // K3 GEMM2 (batched over b): p[b,s,t] = exp((q_b @ k_b^T)/32), col-sums -> Zsum
  gemm256<1><<<dim3(8 * 8, 1, 16), blk512, 0, stream>>>(
      QKV, QKV + 1024, p, Zsum, nullptr,
      /*K*/ DIMD, /*lda*/ 3072, /*ldb*/ 3072, /*ldc*/ SEQN,
      (size_t)SEQN * 3072, (size_t)SEQN * 3072, (size_t)SEQN * SEQN, /*tn*/ 8, 0.03125f);
  // K5: v''[b,l,t] = v[b,t,l] / Zsum[b,t]
  vtrans_kernel<<<dim3(32, 16, 16), blk, 0, stream>>>(QKV, Zsum, vpp);
  // K6 GEMM3 (batched): ftheta[(s*16+b)*1024+l] = p_b @ v''_b^T   (8x4 tiles)
  gemm256<0><<<dim3(8 * 4, 1, 16), blk512, 0, stream>>>(
      p, vpp, fth, nullptr, nullptr,
      /*K*/ SEQN, /*lda*/ SEQN, /*ldb*/ SEQN, /*ldc*/ (size_t)NB * DIMD,
      (size_t)SEQN * SEQN, (size_t)DIMD * SEQN, DIMD, /*tn*/ 4, 0.f);
  // K7 GEMM4: out[s,d,b] = ftheta @ Wg^T + bg   (128x4 tiles)
  gemm256<2><<<dim3(128 * 4, 1, 1), blk512, 0, stream>>>(
      fth, Wgb, nullptr, out, bg,
      /*K*/ DIMD, /*lda*/ DIMD, /*ldb*/ DIMD, /*ldc*/ 0,
      0, 0, 0, /*tn*/ 4, 0.f);
}